// Round 6
// baseline (214.476 us; speedup 1.0000x reference)
//
#include <hip/hip_runtime.h>
#include <hip/hip_bf16.h>
#include <stdint.h>

typedef unsigned short u16;
typedef __attribute__((ext_vector_type(8))) short short8;
typedef __attribute__((ext_vector_type(4))) float f32x4;

#define BATCH 4096
// output region offsets (f32 elements) in d_out: out, h_mix, out_k, h_k
#define OFF_OUT  0
#define OFF_HMIX (BATCH * 256)
#define OFF_OK   (OFF_HMIX + BATCH * 512)
#define OFF_HK   (OFF_OK + BATCH * 256 * 8)

// ws layout (u16/bf16 elements): xb, hb, Wihb, Whhb, Woutb, Tb, Ob (~67 MB)
#define WS_XB   0
#define WS_HB   (2097152)
#define WS_WIH  (4194304)
#define WS_WHH  (6291456)
#define WS_WOUT (8388608)
#define WS_T    (8519680)    // 4096x4096 bf16 plane
#define WS_OB   (25296896)   // 4096x2048 bf16 plane

__device__ __forceinline__ float b2f(u16 v) {
  union { uint32_t u; float f; } c; c.u = ((uint32_t)v) << 16; return c.f;
}
__device__ __forceinline__ u16 f2b(float f) {
  union { float f; uint32_t u; } c; c.f = f;
  uint32_t u = c.u;
  return (u16)((u + 0x7fffu + ((u >> 16) & 1u)) >> 16);  // RNE
}

// async global->LDS, 16B per lane. LDS dest = wave-uniform base + lane*16.
__device__ __forceinline__ void gload16(const u16* g, u16* l) {
  __builtin_amdgcn_global_load_lds(
      (const __attribute__((address_space(1))) void*)g,
      (__attribute__((address_space(3))) void*)l, 16, 0, 0);
}

// ---------------------------------------------------------------------------
// K0: f32 -> bf16 conversion of x, h, W_ih, W_hh, W_out into ws.
// ---------------------------------------------------------------------------
__global__ __launch_bounds__(256) void k0_cvt(
    const float* __restrict__ x, const float* __restrict__ h,
    const float* __restrict__ Wih, const float* __restrict__ Whh,
    const float* __restrict__ Wout, u16* __restrict__ ws) {
  const int i = blockIdx.x * 256 + threadIdx.x;
  const float* src; int j; size_t dst;
  if      (i <  524288) { src = x;    j = i;           dst = WS_XB;   }
  else if (i < 1048576) { src = h;    j = i -  524288; dst = WS_HB;   }
  else if (i < 1572864) { src = Wih;  j = i - 1048576; dst = WS_WIH;  }
  else if (i < 2097152) { src = Whh;  j = i - 1572864; dst = WS_WHH;  }
  else                  { src = Wout; j = i - 2097152; dst = WS_WOUT; }
  const float4 v = ((const float4*)src)[j];
  ushort4 o;
  o.x = f2b(v.x); o.y = f2b(v.y); o.z = f2b(v.z); o.w = f2b(v.w);
  ((ushort4*)(ws + dst))[j] = o;
}

// ---------------------------------------------------------------------------
// K1_FUSED: per block (kk = wg&7 -> one FULL state per XCD; bx = wg>>3):
//   T[128 rows][512 n] = tanh(x·Wih[kk] + h·Whh[kk])      (K-loop, BK=64)
//   store T -> Tb; then mini-GEMM Ob[128][256 y] = T @ Wout^T (K=512)
// replacing the old separate k2 kernel (bit-identical accumulation order).
//
// Geometry: BM=128, BN=512, BK=64, 8 waves (2Mx4N, wave 64x128).
// LDS 144 KiB: A single-buffered [128][64] (16K) + B dbuf 2x[512][64] (128K).
//   A-region is dead after P1 (all A reads in P1) -> restage A(t+1) at P2
//   with 3-phase latency cover. B(t+1) rounds spread P1..P4 (2/phase).
// Counted waits (per-wave vmcnt, always barrier-adjacent before consumption):
//   P2-end vmcnt(6): drains B(t) r4-7 (staged t-1.P3/P4) for P3/P4 reads.
//   P4-end vmcnt(4): drains A(t+1)+B(t+1) r0-3 for t+1.P1/P2 reads;
//   keeps B(t+1) r4-7 in flight. Tail t=15: both 0.
// Phase rhythm identical to the best-measured r3 schedule:
//   {reads; stage; BAR; lgkm0; 16 MFMA; [vmcnt]; BAR}
// ---------------------------------------------------------------------------
__global__ __launch_bounds__(512, 2) void k1_fused(
    const u16* __restrict__ xb, const u16* __restrict__ hb,
    const u16* __restrict__ Wih, const u16* __restrict__ Whh,
    const u16* __restrict__ Wout, u16* __restrict__ Tb,
    u16* __restrict__ Ob) {
  __shared__ u16 S[73728];               // 144 KiB: A[8192] | B0[32768] | B1[32768]
  const int tid  = threadIdx.x;          // 0..511
  const int lane = tid & 63;
  const int w    = tid >> 6;             // 0..7
  const int wm   = w >> 2;               // 0..1  (64-row half)
  const int wn   = w & 3;                // 0..3  (128-col quarter)
  const int quad = lane >> 4, rl = lane & 15, l7 = lane & 7;
  const int sr   = tid >> 3;             // 0..63 staging row
  const int sc   = ((tid & 7) ^ (sr & 7)) * 8;   // swizzled source chunk

  const int wg   = blockIdx.x;
  const int kk   = wg & 7;               // state -> XCD-local (wg%8 = XCD id)
  const int bx   = wg >> 3;              // row tile 0..31
  const int row0 = bx * 128;

  const u16* const As2[2] = { xb, hb };
  const u16* const Bs2[2] = { Wih + (size_t)kk * 262144, Whh + (size_t)kk * 262144 };

  // stage one 64-row round of B (8 KB) / A (8 KB, single-buffered)
  auto stageB = [&](int tile, int r) {
    if (tile >= 16) return;
    const int g = tile >> 3, ko = (tile & 7) * 64;
    gload16(Bs2[g] + (size_t)(r * 64 + sr) * 512 + ko + sc,
            S + 8192 + (tile & 1) * 32768 + r * 4096 + tid * 8);
  };
  auto stageA = [&](int tile, int r) {
    if (tile >= 16) return;
    const int g = tile >> 3, ko = (tile & 7) * 64;
    gload16(As2[g] + (size_t)(row0 + r * 64 + sr) * 512 + ko + sc,
            S + r * 4096 + tid * 8);
  };
  auto ldA = [&](int mi, int ks) -> short8 {
    return *(const short8*)&S[(wm * 64 + mi * 16 + rl) * 64 +
                              ((ks * 4 + quad) ^ l7) * 8];
  };
  auto ldB = [&](int buf, int nj, int ks) -> short8 {
    return *(const short8*)&S[8192 + buf * 32768 +
                              (wn * 128 + nj * 16 + rl) * 64 +
                              ((ks * 4 + quad) ^ l7) * 8];
  };

  f32x4 acc[4][8] = {};

  // prologue: tile0 fully resident
  stageA(0, 0); stageA(0, 1);
#pragma unroll
  for (int r = 0; r < 8; ++r) stageB(0, r);
  asm volatile("s_waitcnt vmcnt(0)" ::: "memory");
  __builtin_amdgcn_s_barrier();

#pragma unroll 1
  for (int t = 0; t < 16; ++t) {
    const int buf = t & 1;
    short8 al[4][2], bf[2][2];

    // ---- P1: al (8) + b n0,1 (4) reads; stage B(t+1) r0-1
#pragma unroll
    for (int m = 0; m < 4; ++m) { al[m][0] = ldA(m, 0); al[m][1] = ldA(m, 1); }
#pragma unroll
    for (int j = 0; j < 2; ++j) { bf[j][0] = ldB(buf, j, 0); bf[j][1] = ldB(buf, j, 1); }
    stageB(t + 1, 0); stageB(t + 1, 1);
    __builtin_amdgcn_s_barrier();
    asm volatile("s_waitcnt lgkmcnt(0)" ::: "memory");
#pragma unroll
    for (int m = 0; m < 4; ++m)
#pragma unroll
      for (int n = 0; n < 2; ++n)
#pragma unroll
        for (int ks = 0; ks < 2; ++ks)
          acc[m][n] = __builtin_amdgcn_mfma_f32_16x16x32_bf16(al[m][ks], bf[n][ks], acc[m][n], 0, 0, 0);
    __builtin_amdgcn_s_barrier();

    // ---- P2: b n2,3; stage A(t+1) (region dead since P1 barrier) + B r2-3
#pragma unroll
    for (int j = 0; j < 2; ++j) { bf[j][0] = ldB(buf, 2 + j, 0); bf[j][1] = ldB(buf, 2 + j, 1); }
    stageA(t + 1, 0); stageA(t + 1, 1);
    stageB(t + 1, 2); stageB(t + 1, 3);
    __builtin_amdgcn_s_barrier();
    asm volatile("s_waitcnt lgkmcnt(0)" ::: "memory");
#pragma unroll
    for (int m = 0; m < 4; ++m)
#pragma unroll
      for (int n = 0; n < 2; ++n)
#pragma unroll
        for (int ks = 0; ks < 2; ++ks)
          acc[m][2 + n] = __builtin_amdgcn_mfma_f32_16x16x32_bf16(al[m][ks], bf[n][ks], acc[m][2 + n], 0, 0, 0);
    // guarantee B(t) r4-7 (staged t-1.P3/P4) block-wide after this barrier
    if (t < 15) asm volatile("s_waitcnt vmcnt(6)" ::: "memory");
    else        asm volatile("s_waitcnt vmcnt(0)" ::: "memory");
    __builtin_amdgcn_s_barrier();

    // ---- P3: b n4,5; stage B(t+1) r4-5
#pragma unroll
    for (int j = 0; j < 2; ++j) { bf[j][0] = ldB(buf, 4 + j, 0); bf[j][1] = ldB(buf, 4 + j, 1); }
    stageB(t + 1, 4); stageB(t + 1, 5);
    __builtin_amdgcn_s_barrier();
    asm volatile("s_waitcnt lgkmcnt(0)" ::: "memory");
#pragma unroll
    for (int m = 0; m < 4; ++m)
#pragma unroll
      for (int n = 0; n < 2; ++n)
#pragma unroll
        for (int ks = 0; ks < 2; ++ks)
          acc[m][4 + n] = __builtin_amdgcn_mfma_f32_16x16x32_bf16(al[m][ks], bf[n][ks], acc[m][4 + n], 0, 0, 0);
    __builtin_amdgcn_s_barrier();

    // ---- P4: b n6,7; stage B(t+1) r6-7; boundary wait
#pragma unroll
    for (int j = 0; j < 2; ++j) { bf[j][0] = ldB(buf, 6 + j, 0); bf[j][1] = ldB(buf, 6 + j, 1); }
    stageB(t + 1, 6); stageB(t + 1, 7);
    __builtin_amdgcn_s_barrier();
    asm volatile("s_waitcnt lgkmcnt(0)" ::: "memory");
#pragma unroll
    for (int m = 0; m < 4; ++m)
#pragma unroll
      for (int n = 0; n < 2; ++n)
#pragma unroll
        for (int ks = 0; ks < 2; ++ks)
          acc[m][6 + n] = __builtin_amdgcn_mfma_f32_16x16x32_bf16(al[m][ks], bf[n][ks], acc[m][6 + n], 0, 0, 0);
    // drain A(t+1)+B(t+1) r0-3; keep B(t+1) r4-7 in flight
    if (t < 15) asm volatile("s_waitcnt vmcnt(4)" ::: "memory");
    else        asm volatile("s_waitcnt vmcnt(0)" ::: "memory");
    __builtin_amdgcn_s_barrier();
  }

  // ---- epilogue (a): tanh -> bf16 -> T-LDS [128][520] (2-way banks, free)
#pragma unroll
  for (int mi = 0; mi < 4; ++mi)
#pragma unroll
    for (int nj = 0; nj < 8; ++nj)
#pragma unroll
      for (int r = 0; r < 4; ++r) {
        const int row = wm * 64 + mi * 16 + quad * 4 + r;
        const int col = wn * 128 + nj * 16 + rl;
        const float v = acc[mi][nj][r];
        const float e = __expf(2.0f * v);          // tanh, saturating, no NaN
        S[row * 520 + col] = f2b(1.0f - 2.0f / (e + 1.0f));
      }
  asm volatile("s_waitcnt lgkmcnt(0)" ::: "memory");
  __builtin_amdgcn_s_barrier();

  // ---- (b): store T (coalesced 16B, rows of 1 KB)
#pragma unroll
  for (int p = 0; p < 16; ++p) {
    const int idx = p * 512 + tid;     // 0..8191
    const int c = idx & 63, rr = idx >> 6;
    *(short8*)&Tb[(size_t)(row0 + rr) * 4096 + kk * 512 + c * 8] =
        *(const short8*)&S[rr * 520 + c * 8];
  }

  // ---- (c): mini-GEMM Ob_tile[128][256] = T @ Wout^T, K=512 in 8 chunks.
  // B-frags straight from global (L2-hot Wout, 64B row segments); A from T-LDS.
  // Chunk order (c2, ks2) == old k2's (kt, ks) -> bit-identical Ob.
  f32x4 acc2[4][4] = {};
#pragma unroll 2
  for (int c2 = 0; c2 < 8; ++c2) {
    short8 b2[4][2], a2[4][2];
#pragma unroll
    for (int nj = 0; nj < 4; ++nj)
#pragma unroll
      for (int ks = 0; ks < 2; ++ks)
        b2[nj][ks] = *(const short8*)&Wout[(size_t)(wn * 64 + nj * 16 + rl) * 512 +
                                           c2 * 64 + ks * 32 + quad * 8];
#pragma unroll
    for (int mi = 0; mi < 4; ++mi)
#pragma unroll
      for (int ks = 0; ks < 2; ++ks)
        a2[mi][ks] = *(const short8*)&S[(wm * 64 + mi * 16 + rl) * 520 +
                                        c2 * 64 + ks * 32 + quad * 8];
#pragma unroll
    for (int mi = 0; mi < 4; ++mi)
#pragma unroll
      for (int nj = 0; nj < 4; ++nj)
#pragma unroll
        for (int ks = 0; ks < 2; ++ks)
          acc2[mi][nj] = __builtin_amdgcn_mfma_f32_16x16x32_bf16(a2[mi][ks], b2[nj][ks], acc2[mi][nj], 0, 0, 0);
  }
  asm volatile("s_waitcnt lgkmcnt(0)" ::: "memory");
  __builtin_amdgcn_s_barrier();

  // ---- (d): Ob transpose via LDS [128][264] -> coalesced 16B stores
#pragma unroll
  for (int mi = 0; mi < 4; ++mi)
#pragma unroll
    for (int nj = 0; nj < 4; ++nj)
#pragma unroll
      for (int r = 0; r < 4; ++r) {
        const int row = wm * 64 + mi * 16 + quad * 4 + r;
        const int col = wn * 64 + nj * 16 + rl;
        S[row * 264 + col] = f2b(acc2[mi][nj][r]);
      }
  asm volatile("s_waitcnt lgkmcnt(0)" ::: "memory");
  __builtin_amdgcn_s_barrier();
#pragma unroll
  for (int p = 0; p < 8; ++p) {
    const int idx = p * 512 + tid;     // 0..4095
    const int c = idx & 31, rr = idx >> 5;
    *(short8*)&Ob[(size_t)(row0 + rr) * 2048 + kk * 256 + c * 8] =
        *(const short8*)&S[rr * 264 + c * 8];
  }
}

// ---------------------------------------------------------------------------
// K3: epilogue. Block b: reads Tb row + Ob row (bf16, ws), writes f32
// interleaved h_k / out_k (coalesced float4) + h_mix + out.
// ---------------------------------------------------------------------------
__global__ __launch_bounds__(512) void k3_epi(const float* __restrict__ pi,
                                              const u16* __restrict__ Tb,
                                              const u16* __restrict__ Ob,
                                              float* __restrict__ dout) {
  const int b   = blockIdx.x;
  const int tid = threadIdx.x;

  float pif[8];
#pragma unroll
  for (int k = 0; k < 8; ++k) pif[k] = pi[b * 8 + k];

  float tv[8]; float hm = 0.0f;
#pragma unroll
  for (int k = 0; k < 8; ++k) {
    const float v = b2f(Tb[(size_t)b * 4096 + k * 512 + tid]);
    tv[k] = v; hm += pif[k] * v;
  }
  float4* tw = (float4*)&dout[OFF_HK + (size_t)b * 4096 + tid * 8];
  tw[0] = make_float4(tv[0], tv[1], tv[2], tv[3]);
  tw[1] = make_float4(tv[4], tv[5], tv[6], tv[7]);
  dout[OFF_HMIX + (size_t)b * 512 + tid] = hm;

  if (tid < 256) {
    float ov[8]; float om = 0.0f;
#pragma unroll
    for (int k = 0; k < 8; ++k) {
      const float v = b2f(Ob[(size_t)b * 2048 + k * 256 + tid]);
      ov[k] = v; om += pif[k] * v;
    }
    float4* ow = (float4*)&dout[OFF_OK + (size_t)b * 2048 + tid * 8];
    ow[0] = make_float4(ov[0], ov[1], ov[2], ov[3]);
    ow[1] = make_float4(ov[4], ov[5], ov[6], ov[7]);
    dout[OFF_OUT + (size_t)b * 256 + tid] = om;
  }
}

extern "C" void kernel_launch(void* const* d_in, const int* in_sizes, int n_in,
                              void* d_out, int out_size, void* d_ws, size_t ws_size,
                              hipStream_t stream) {
  const float* x    = (const float*)d_in[0];
  const float* h    = (const float*)d_in[1];
  const float* pi   = (const float*)d_in[2];
  const float* Wih  = (const float*)d_in[3];
  const float* Whh  = (const float*)d_in[4];
  const float* Wout = (const float*)d_in[5];
  float* out = (float*)d_out;
  u16* ws  = (u16*)d_ws;

  k0_cvt<<<dim3(8320), 256, 0, stream>>>(x, h, Wih, Whh, Wout, ws);
  k1_fused<<<dim3(256), 512, 0, stream>>>(
      ws + WS_XB, ws + WS_HB, ws + WS_WIH, ws + WS_WHH, ws + WS_WOUT,
      ws + WS_T, ws + WS_OB);
  k3_epi<<<dim3(BATCH), 512, 0, stream>>>(pi, ws + WS_T, ws + WS_OB, out);
}